// Round 4
// baseline (312.129 us; speedup 1.0000x reference)
//
#include <hip/hip_runtime.h>
#include <math.h>

#define NNODES 8192
#define DIM 256
#define ALPHA 3.0f
#define SLOPE 0.2f
#define LOG2E 1.4426950408889634f

typedef float floatx4 __attribute__((ext_vector_type(4)));

// ---------------------------------------------------------------------------
// Kernel A: per-node scores s1[n] = tanh(a*emb1[idx[n]]) . w[:256]
//                           s2[n] = tanh(a*emb2[idx[n]]) . w[256:]
// One wave (64 lanes) per node; each lane handles 4 contiguous floats.
// (Round-1 lesson: NO single-address atomics — 8192 same-line device-scope
// atomicMax ops serialized for ~90 us across 8 XCDs.)
// ---------------------------------------------------------------------------
__global__ __launch_bounds__(256) void s_kernel(
    const int* __restrict__ idx,
    const float* __restrict__ e1, const float* __restrict__ e2,
    const float* __restrict__ w,
    float* __restrict__ s1, float* __restrict__ s2)
{
    const int waveId = threadIdx.x >> 6;
    const int lane   = threadIdx.x & 63;
    const int node   = (blockIdx.x << 2) + waveId;   // 4 waves/block
    const int row    = idx[node];

    const float4* e1v = (const float4*)(e1 + (size_t)row * DIM);
    const float4* e2v = (const float4*)(e2 + (size_t)row * DIM);
    const float4* w1v = (const float4*)w;
    const float4* w2v = (const float4*)(w + DIM);

    float4 a  = e1v[lane];
    float4 b  = e2v[lane];
    float4 w1 = w1v[lane];
    float4 w2 = w2v[lane];

    float acc1 = tanhf(ALPHA * a.x) * w1.x + tanhf(ALPHA * a.y) * w1.y
               + tanhf(ALPHA * a.z) * w1.z + tanhf(ALPHA * a.w) * w1.w;
    float acc2 = tanhf(ALPHA * b.x) * w2.x + tanhf(ALPHA * b.y) * w2.y
               + tanhf(ALPHA * b.z) * w2.z + tanhf(ALPHA * b.w) * w2.w;

    #pragma unroll
    for (int off = 32; off > 0; off >>= 1) {
        acc1 += __shfl_down(acc1, off);
        acc2 += __shfl_down(acc2, off);
    }
    if (lane == 0) {
        s1[node] = acc1;
        s2[node] = acc2;
    }
}

// ---------------------------------------------------------------------------
// Kernel B: denom_kernel — storeless compute phase, wave-per-row.
// Round-3 post-mortem: with all 2048 blocks co-resident the fused kernel was
// phase-serial chip-wide (max pass + denom pass ran with the store pipe idle,
// ~12-15 us). Moving those passes here lets kernel C be a pure store stream.
//
// Per row: m_i = lr(s1[i]+b+max_j s2[j]) (exact: lr strictly increasing),
// denominator via bit-identical loop/butterfly to round 3, writes
// base/mexp/inv (3 floats/row).
// idx-identity check runs in BLOCK 0 ONLY (one 32 KB scan) — keeps idx out
// of the other 2047 blocks' L1 so s2 (32 KB) fits L1 exactly.
// ---------------------------------------------------------------------------
__global__ __launch_bounds__(256) void denom_kernel(
    const float* __restrict__ s1, const float* __restrict__ s2,
    const int* __restrict__ idx, const float* __restrict__ att_b,
    float* __restrict__ base_out, float* __restrict__ mexp_out,
    float* __restrict__ inv_out, int* __restrict__ ok_out)
{
    const int lane = threadIdx.x & 63;
    const int wv   = threadIdx.x >> 6;
    const int row  = (blockIdx.x << 2) + wv;   // 4 rows per block

    const float4* s2v = (const float4*)s2;

    // global max of s2 (every wave computes the same value; bit-identical
    // to round 3's pass 0)
    float lmax = -3.402823466e38f;
    #pragma unroll 4
    for (int k = 0; k < 32; ++k) {
        float4 v = s2v[k * 64 + lane];
        lmax = fmaxf(lmax, fmaxf(fmaxf(v.x, v.y), fmaxf(v.z, v.w)));
    }
    #pragma unroll
    for (int off = 32; off > 0; off >>= 1)
        lmax = fmaxf(lmax, __shfl_xor(lmax, off));

    const float base = s1[row] + att_b[0];
    const float tm   = base + lmax;
    const float m    = fmaxf(tm, SLOPE * tm);    // exact row max of lr(scores)
    const float mexp = m * LOG2E;

    // softmax denominator (bit-identical sequence to round 3's pass 1)
    float dsum = 0.0f;
    #pragma unroll 4
    for (int k = 0; k < 32; ++k) {
        float4 v = s2v[k * 64 + lane];
        float x0 = base + v.x, x1 = base + v.y;
        float x2 = base + v.z, x3 = base + v.w;
        x0 = fmaxf(x0, SLOPE * x0);
        x1 = fmaxf(x1, SLOPE * x1);
        x2 = fmaxf(x2, SLOPE * x2);
        x3 = fmaxf(x3, SLOPE * x3);
        float e0 = __builtin_amdgcn_exp2f(fmaf(x0, LOG2E, -mexp));
        float e1 = __builtin_amdgcn_exp2f(fmaf(x1, LOG2E, -mexp));
        float e2 = __builtin_amdgcn_exp2f(fmaf(x2, LOG2E, -mexp));
        float e3 = __builtin_amdgcn_exp2f(fmaf(x3, LOG2E, -mexp));
        dsum += (e0 + e1) + (e2 + e3);
    }
    #pragma unroll
    for (int off = 32; off > 0; off >>= 1)
        dsum += __shfl_xor(dsum, off);
    if (lane == 0) {
        base_out[row] = base;
        mexp_out[row] = mexp;
        inv_out[row]  = 1.0f / dsum;
    }

    // idx == arange check: block 0 only
    if (blockIdx.x == 0) {
        __shared__ int sok[4];
        const int t = threadIdx.x;
        const int4* idxv = (const int4*)idx;
        int ok = 1;
        #pragma unroll
        for (int k = 0; k < 8; ++k) {
            int4 iv = idxv[k * 256 + t];
            const int c0 = (k * 256 + t) * 4;
            ok &= (iv.x == c0) & (iv.y == c0 + 1) & (iv.z == c0 + 2) & (iv.w == c0 + 3);
        }
        #pragma unroll
        for (int off = 32; off > 0; off >>= 1)
            ok &= __shfl_xor(ok, off);
        if (lane == 0) sok[wv] = ok;
        __syncthreads();
        if (t == 0) ok_out[0] = sok[0] & sok[1] & sok[2] & sok[3];
    }
}

// ---------------------------------------------------------------------------
// Kernel C: row_kernel — PURE STORE STREAM, wave-per-row, single pass.
// Loads 3 per-row scalars + 1 global flag, then loops {L1-hit s2 float4 load,
// 4 exp2, nontemporal float4 store}. Store pipe busy from iteration 1; shaped
// like the harness fill that sustains 6.4 TB/s. ~30 VGPR -> max occupancy.
// ---------------------------------------------------------------------------
__global__ __launch_bounds__(256) void row_kernel(
    const float* __restrict__ s2, const int* __restrict__ idx,
    const float* __restrict__ base_p, const float* __restrict__ mexp_p,
    const float* __restrict__ inv_p, const int* __restrict__ ok_p,
    float* __restrict__ out)
{
    const int lane = threadIdx.x & 63;
    const int wv   = threadIdx.x >> 6;
    const int row  = (blockIdx.x << 2) + wv;   // 4 rows per block

    const float base = base_p[row];
    const float mexp = mexp_p[row];
    const float inv  = inv_p[row];
    const int   ok   = ok_p[0];

    const float4* s2v = (const float4*)s2;
    float* orow = out + (size_t)row * NNODES;

    if (ok) {
        // Fast path: computed-address nontemporal float4 stream.
        #pragma unroll 4
        for (int k = 0; k < 32; ++k) {
            float4 v = s2v[k * 64 + lane];
            float x0 = base + v.x, x1 = base + v.y;
            float x2 = base + v.z, x3 = base + v.w;
            x0 = fmaxf(x0, SLOPE * x0);
            x1 = fmaxf(x1, SLOPE * x1);
            x2 = fmaxf(x2, SLOPE * x2);
            x3 = fmaxf(x3, SLOPE * x3);
            floatx4 o;
            o.x = __builtin_amdgcn_exp2f(fmaf(x0, LOG2E, -mexp)) * inv;
            o.y = __builtin_amdgcn_exp2f(fmaf(x1, LOG2E, -mexp)) * inv;
            o.z = __builtin_amdgcn_exp2f(fmaf(x2, LOG2E, -mexp)) * inv;
            o.w = __builtin_amdgcn_exp2f(fmaf(x3, LOG2E, -mexp)) * inv;
            __builtin_nontemporal_store(o, (floatx4*)(orow + (k * 64 + lane) * 4));
        }
    } else {
        // General path: scatter via idx (L1/L2-resident).
        const int4* idxv = (const int4*)idx;
        #pragma unroll 4
        for (int k = 0; k < 32; ++k) {
            float4 v = s2v[k * 64 + lane];
            int4  iv = idxv[k * 64 + lane];
            float x0 = base + v.x, x1 = base + v.y;
            float x2 = base + v.z, x3 = base + v.w;
            x0 = fmaxf(x0, SLOPE * x0);
            x1 = fmaxf(x1, SLOPE * x1);
            x2 = fmaxf(x2, SLOPE * x2);
            x3 = fmaxf(x3, SLOPE * x3);
            orow[iv.x] = __builtin_amdgcn_exp2f(fmaf(x0, LOG2E, -mexp)) * inv;
            orow[iv.y] = __builtin_amdgcn_exp2f(fmaf(x1, LOG2E, -mexp)) * inv;
            orow[iv.z] = __builtin_amdgcn_exp2f(fmaf(x2, LOG2E, -mexp)) * inv;
            orow[iv.w] = __builtin_amdgcn_exp2f(fmaf(x3, LOG2E, -mexp)) * inv;
        }
    }
}

extern "C" void kernel_launch(void* const* d_in, const int* in_sizes, int n_in,
                              void* d_out, int out_size, void* d_ws, size_t ws_size,
                              hipStream_t stream) {
    const int*   idx   = (const int*)d_in[0];
    const float* emb1  = (const float*)d_in[1];
    const float* emb2  = (const float*)d_in[2];
    const float* att_w = (const float*)d_in[3];
    const float* att_b = (const float*)d_in[4];
    float* out = (float*)d_out;

    float* s1   = (float*)d_ws;          // 8192 floats
    float* s2   = s1 + NNODES;           // 8192 floats
    float* base = s2 + NNODES;           // 8192 floats
    float* mexp = base + NNODES;         // 8192 floats
    float* inv  = mexp + NNODES;         // 8192 floats
    int*   okf  = (int*)(inv + NNODES);  // 1 int

    s_kernel    <<<NNODES / 4, 256, 0, stream>>>(idx, emb1, emb2, att_w, s1, s2);
    denom_kernel<<<NNODES / 4, 256, 0, stream>>>(s1, s2, idx, att_b, base, mexp, inv, okf);
    row_kernel  <<<NNODES / 4, 256, 0, stream>>>(s2, idx, base, mexp, inv, okf, out);
}

// Round 5
// 293.836 us; speedup vs baseline: 1.0623x; 1.0623x over previous
//
#include <hip/hip_runtime.h>
#include <math.h>

#define NNODES 8192
#define DIM 256
#define ALPHA 3.0f
#define SLOPE 0.2f
#define LOG2E 1.4426950408889634f
#define ROWS_PER_BLOCK 8

typedef float floatx4 __attribute__((ext_vector_type(4)));

// ---------------------------------------------------------------------------
// Kernel A: per-node scores s1[n] = tanh(a*emb1[idx[n]]) . w[:256]
//                           s2[n] = tanh(a*emb2[idx[n]]) . w[256:]
// One wave (64 lanes) per node; each lane handles 4 contiguous floats.
// (Round-1 lesson: NO single-address atomics — 8192 same-line device-scope
// atomicMax ops serialized for ~90 us across 8 XCDs.)
// ---------------------------------------------------------------------------
__global__ __launch_bounds__(256) void s_kernel(
    const int* __restrict__ idx,
    const float* __restrict__ e1, const float* __restrict__ e2,
    const float* __restrict__ w,
    float* __restrict__ s1, float* __restrict__ s2)
{
    const int waveId = threadIdx.x >> 6;
    const int lane   = threadIdx.x & 63;
    const int node   = (blockIdx.x << 2) + waveId;   // 4 waves/block
    const int row    = idx[node];

    const float4* e1v = (const float4*)(e1 + (size_t)row * DIM);
    const float4* e2v = (const float4*)(e2 + (size_t)row * DIM);
    const float4* w1v = (const float4*)w;
    const float4* w2v = (const float4*)(w + DIM);

    float4 a  = e1v[lane];
    float4 b  = e2v[lane];
    float4 w1 = w1v[lane];
    float4 w2 = w2v[lane];

    float acc1 = tanhf(ALPHA * a.x) * w1.x + tanhf(ALPHA * a.y) * w1.y
               + tanhf(ALPHA * a.z) * w1.z + tanhf(ALPHA * a.w) * w1.w;
    float acc2 = tanhf(ALPHA * b.x) * w2.x + tanhf(ALPHA * b.y) * w2.y
               + tanhf(ALPHA * b.z) * w2.z + tanhf(ALPHA * b.w) * w2.w;

    #pragma unroll
    for (int off = 32; off > 0; off >>= 1) {
        acc1 += __shfl_down(acc1, off);
        acc2 += __shfl_down(acc2, off);
    }
    if (lane == 0) {
        s1[node] = acc1;
        s2[node] = acc2;
    }
}

// ---------------------------------------------------------------------------
// Kernel B: MULTI-ROW block (8 rows), register-resident s2 slice.
//
//   scores[i,j] = leaky_relu(s1[i] + s2[j] + b)   (lr(x) = max(x, 0.2x))
//   m_i = lr(s1[i] + b + max_j s2[j])             (exact: lr increasing)
//   out[i, idx[j]] = exp(scores - m_i) / sum_j exp(...)
//
// Round-4 post-mortem: every prior structure re-read all of s2/idx from
// L1/L2 once or twice PER ROW (128 MB of cache reads chip-wide) inside
// store-idle phases. But per-thread the s2 slice is ROW-INVARIANT under
// block-per-row tiling: thread t's 32 values serve all 8 rows.
//
// One-time per block: load v[8] (32 s2 floats), fused s2-max scan and
// idx==arange check (idx regs die immediately). Then per row: pure register
// compute (32 exp2, butterfly, ONE barrier via double-buffered LDS slots),
// then 8 NT float4 stores. No loads in the steady loop except s1[row].
// Row r's fire-and-forget store burst drains underneath row r+1's exp
// compute -> store pipe duty cycle ~100% after a ~1-row warmup.
// ~96 VGPR -> all 4 blocks/CU resident.
// ---------------------------------------------------------------------------
__global__ __launch_bounds__(256) void row_kernel(
    const float* __restrict__ s1, const float* __restrict__ s2,
    const int* __restrict__ idx, const float* __restrict__ att_b,
    float* __restrict__ out)
{
    __shared__ float red[8];    // denominator slots, double-buffered by row parity
    __shared__ float rmax[4];
    __shared__ int   rok[4];
    const int t    = threadIdx.x;
    const int lane = t & 63;
    const int wv   = t >> 6;
    const int row0 = blockIdx.x * ROWS_PER_BLOCK;

    // One-time: load s2 slice into registers; fused global-max + identity scan.
    const float4* s2v = (const float4*)s2;
    float4 v[8];
    float lmax = -3.402823466e38f;
    int ok = 1;
    {
        const int4* idxv = (const int4*)idx;
        #pragma unroll
        for (int k = 0; k < 8; ++k) {
            v[k] = s2v[k * 256 + t];
            lmax = fmaxf(lmax, fmaxf(fmaxf(v[k].x, v[k].y), fmaxf(v[k].z, v[k].w)));
            int4 iv = idxv[k * 256 + t];
            const int c0 = (k * 256 + t) * 4;
            ok &= (iv.x == c0) & (iv.y == c0 + 1) & (iv.z == c0 + 2) & (iv.w == c0 + 3);
        }
    }
    #pragma unroll
    for (int off = 32; off > 0; off >>= 1) {
        lmax = fmaxf(lmax, __shfl_xor(lmax, off));
        ok &= __shfl_xor(ok, off);
    }
    if (lane == 0) { rmax[wv] = lmax; rok[wv] = ok; }
    __syncthreads();
    const float s2max = fmaxf(fmaxf(rmax[0], rmax[1]), fmaxf(rmax[2], rmax[3]));
    const int   okAll = rok[0] & rok[1] & rok[2] & rok[3];
    const float bb    = att_b[0];

    float e[32];
    for (int r = 0; r < ROWS_PER_BLOCK; ++r) {
        const int row   = row0 + r;
        const float base = s1[row] + bb;
        const float tm   = base + s2max;
        const float m    = fmaxf(tm, SLOPE * tm);   // exact row max of lr(scores)
        const float mexp = m * LOG2E;

        // exp pass: pure register compute (v[] row-invariant)
        float dsum = 0.0f;
        #pragma unroll
        for (int k = 0; k < 8; ++k) {
            float x0 = base + v[k].x, x1 = base + v[k].y;
            float x2 = base + v[k].z, x3 = base + v[k].w;
            x0 = fmaxf(x0, SLOPE * x0);
            x1 = fmaxf(x1, SLOPE * x1);
            x2 = fmaxf(x2, SLOPE * x2);
            x3 = fmaxf(x3, SLOPE * x3);
            e[4 * k + 0] = __builtin_amdgcn_exp2f(fmaf(x0, LOG2E, -mexp));
            e[4 * k + 1] = __builtin_amdgcn_exp2f(fmaf(x1, LOG2E, -mexp));
            e[4 * k + 2] = __builtin_amdgcn_exp2f(fmaf(x2, LOG2E, -mexp));
            e[4 * k + 3] = __builtin_amdgcn_exp2f(fmaf(x3, LOG2E, -mexp));
            dsum += (e[4 * k + 0] + e[4 * k + 1]) + (e[4 * k + 2] + e[4 * k + 3]);
        }
        #pragma unroll
        for (int off = 32; off > 0; off >>= 1)
            dsum += __shfl_xor(dsum, off);

        // ONE barrier per row: parity-selected LDS slots (row r's post-barrier
        // read can't race row r+2's write — the writer must first pass row
        // r+1's barrier, which the reader only reaches after this read).
        float* slot = red + ((r & 1) << 2);
        if (lane == 0) slot[wv] = dsum;
        __syncthreads();
        const float denom = (slot[0] + slot[1]) + (slot[2] + slot[3]);
        const float inv = 1.0f / denom;

        float* orow = out + (size_t)row * NNODES;
        if (okAll) {
            // Fast path: computed-address NT float4 stream, values from regs.
            #pragma unroll
            for (int k = 0; k < 8; ++k) {
                floatx4 o;
                o.x = e[4 * k + 0] * inv;
                o.y = e[4 * k + 1] * inv;
                o.z = e[4 * k + 2] * inv;
                o.w = e[4 * k + 3] * inv;
                __builtin_nontemporal_store(o, (floatx4*)(orow + (k * 256 + t) * 4));
            }
        } else {
            // General path: scatter via idx (L2-resident; benchmark never takes this).
            const int4* idxv = (const int4*)idx;
            #pragma unroll
            for (int k = 0; k < 8; ++k) {
                int4 iv = idxv[k * 256 + t];
                orow[iv.x] = e[4 * k + 0] * inv;
                orow[iv.y] = e[4 * k + 1] * inv;
                orow[iv.z] = e[4 * k + 2] * inv;
                orow[iv.w] = e[4 * k + 3] * inv;
            }
        }
    }
}

extern "C" void kernel_launch(void* const* d_in, const int* in_sizes, int n_in,
                              void* d_out, int out_size, void* d_ws, size_t ws_size,
                              hipStream_t stream) {
    const int*   idx   = (const int*)d_in[0];
    const float* emb1  = (const float*)d_in[1];
    const float* emb2  = (const float*)d_in[2];
    const float* att_w = (const float*)d_in[3];
    const float* att_b = (const float*)d_in[4];
    float* out = (float*)d_out;

    float* s1 = (float*)d_ws;          // 8192 floats
    float* s2 = s1 + NNODES;           // 8192 floats

    s_kernel  <<<NNODES / 4, 256, 0, stream>>>(idx, emb1, emb2, att_w, s1, s2);
    row_kernel<<<NNODES / ROWS_PER_BLOCK, 256, 0, stream>>>(s1, s2, idx, att_b, out);
}